// Round 9
// baseline (320.545 us; speedup 1.0000x reference)
//
#include <hip/hip_runtime.h>
#include <hip/hip_bf16.h>

// Problem constants
#define BB 8
#define CC 128
#define NN 16384            // 128*128 tokens per batch
#define MM (BB * NN)        // 131072
#define NCH 128             // scan chunks per batch-row
#define CLN 128             // chunk length == GEMM tile M

typedef __attribute__((ext_vector_type(8))) short short8;   // 8 x bf16 (4 VGPRs)
typedef __attribute__((ext_vector_type(4))) float floatx4;  // MFMA accumulator
typedef unsigned short u16;
typedef unsigned int u32;

__device__ __forceinline__ float bf2f(u16 h) {
  u32 u = ((u32)h) << 16;
  return __builtin_bit_cast(float, u);
}
__device__ __forceinline__ u16 f2bf(float f) {
  u32 u = __builtin_bit_cast(u32, f);
  u32 r = u + 0x7FFFu + ((u >> 16) & 1u);   // round-to-nearest-even
  return (u16)(r >> 16);
}

// ---------------------------------------------------------------------------
// FiLM params: gamma[b,c] = gs[b,:]·cond_gw[c,:] + cond_gb[c]; beta likewise.
__global__ void film_kernel(const float* __restrict__ gs, const float* __restrict__ gw,
                            const float* __restrict__ gb, const float* __restrict__ bw,
                            const float* __restrict__ bb, float* __restrict__ gamma,
                            float* __restrict__ beta) {
  int idx = blockIdx.x * 256 + threadIdx.x;   // 0..1023
  int b = idx >> 7, c = idx & 127;
  float sg = 0.f, sb = 0.f;
  for (int j = 0; j < 128; ++j) {
    float g = gs[b * 128 + j];
    sg += g * gw[c * 128 + j];
    sb += g * bw[c * 128 + j];
  }
  gamma[idx] = sg + gb[c];
  beta[idx] = sb + bb[c];
}

// ---------------------------------------------------------------------------
// Convert all 6 weight tensors (each (2,128,128) f32) to bf16, packed
// [which][block][o][c] at dst + which*32768.
__global__ void convert_kernel(const float* __restrict__ Wk, const float* __restrict__ Wv,
                               const float* __restrict__ Wr, const float* __restrict__ Wo,
                               const float* __restrict__ gp, const float* __restrict__ bp,
                               u16* __restrict__ dst) {
  int idx = blockIdx.x * 256 + threadIdx.x;   // 0..196607
  int which = idx >> 15;
  int off = idx & 32767;
  const float* s;
  switch (which) {
    case 0: s = Wk; break; case 1: s = Wv; break; case 2: s = Wr; break;
    case 3: s = Wo; break; case 4: s = gp; break; default: s = bp; break;
  }
  dst[idx] = f2bf(s[off]);
}

// ---------------------------------------------------------------------------
// Prep: (UPS=1) bilinear 2x upsample + write x_up to out(BCHW) + FiLM + LN -> xn bf16
//       (UPS=0) read out(BCHW) + LN -> xn bf16
template <int UPS>
__global__ __launch_bounds__(256) void prep_kernel(
    const float* __restrict__ src, const float* __restrict__ gamma,
    const float* __restrict__ beta, const float* __restrict__ lng,
    const float* __restrict__ lnb, float* __restrict__ outp, u16* __restrict__ xn) {
  __shared__ float tile[64][129];
  __shared__ float smu[64], srs[64];
  int bidx = blockIdx.x;              // 0..2047
  int half = bidx & 1;
  int ho = (bidx >> 1) & 127;
  int b = bidx >> 8;
  int wo0 = half * 64;
  int tid = threadIdx.x;
  int tk = tid & 63;
  int wo = wo0 + tk;
  int c0 = tid >> 6;                  // 0..3
  int j0 = 0, j1 = 0, i0 = 0, i1 = 0;
  float wy0 = 0.f, wy1 = 0.f, wx0 = 0.f, wx1 = 0.f;
  if (UPS) {
    int jj = ho >> 1;
    if ((ho & 1) == 0) { j0 = jj > 0 ? jj - 1 : 0; j1 = jj; wy0 = 0.25f; wy1 = 0.75f; }
    else               { j0 = jj; j1 = jj < 63 ? jj + 1 : 63; wy0 = 0.75f; wy1 = 0.25f; }
    int ii = wo >> 1;
    if ((wo & 1) == 0) { i0 = ii > 0 ? ii - 1 : 0; i1 = ii; wx0 = 0.25f; wx1 = 0.75f; }
    else               { i0 = ii; i1 = ii < 63 ? ii + 1 : 63; wx0 = 0.75f; wx1 = 0.25f; }
  }
  for (int it = 0; it < 32; ++it) {
    int c = it * 4 + c0;
    float v;
    if (UPS) {
      const float* xp = src + ((size_t)(b * 128 + c)) * 4096;
      v = wy0 * (wx0 * xp[j0 * 64 + i0] + wx1 * xp[j0 * 64 + i1]) +
          wy1 * (wx0 * xp[j1 * 64 + i0] + wx1 * xp[j1 * 64 + i1]);
      outp[((size_t)(b * 128 + c)) * 16384 + ho * 128 + wo] = v;
      v = v * (1.f + gamma[b * 128 + c]) + beta[b * 128 + c];
    } else {
      v = src[((size_t)(b * 128 + c)) * 16384 + ho * 128 + wo];
    }
    tile[tk][c] = v;
  }
  __syncthreads();
  {
    int token = tid >> 2, q = tid & 3;
    float s = 0.f, s2 = 0.f;
    for (int j = 0; j < 32; ++j) { float v = tile[token][q * 32 + j]; s += v; s2 += v * v; }
    s += __shfl_xor(s, 1); s2 += __shfl_xor(s2, 1);
    s += __shfl_xor(s, 2); s2 += __shfl_xor(s2, 2);
    if (q == 0) {
      float mu = s * 0.0078125f;
      float var = s2 * 0.0078125f - mu * mu;
      smu[token] = mu;
      srs[token] = rsqrtf(var + 1e-5f);
    }
  }
  __syncthreads();
  size_t base = ((size_t)b * 16384 + ho * 128 + wo0) * 128;
  for (int it = 0; it < 32; ++it) {
    int idx = it * 256 + tid;
    int token = idx >> 7, c = idx & 127;
    float v = (tile[token][c] - smu[token]) * srs[token] * lng[c] + lnb[c];
    xn[base + idx] = f2bf(v);
  }
}

// ---------------------------------------------------------------------------
// gemm_S: k-GEMM only (B fragments direct from global/L2), fused decay-weighted
// chunk sum -> Sbuf. 34 KB LDS -> 4 blocks/CU.
__global__ __launch_bounds__(256) void gemm_S_kernel(
    const u16* __restrict__ A, const u16* __restrict__ W0,
    const float* __restrict__ td, float* __restrict__ Sbuf) {
  __shared__ u16 Alds[128 * 128];
  __shared__ float Sred[512];         // [wave][c]
  int tid = threadIdx.x;
  int wave = tid >> 6, lane = tid & 63;
  int l15 = lane & 15, l4 = lane >> 4;
  size_t row0 = (size_t)blockIdx.x * 128;
#pragma unroll
  for (int it = 0; it < 8; ++it) {
    int idx = it * 256 + tid;
    int rr = idx >> 4, s = idx & 15;
    uint4 d = *(const uint4*)(A + (row0 + rr) * 128 + s * 8);
    *(uint4*)(&Alds[rr * 128 + ((s ^ (rr & 15)) << 3)]) = d;
  }
  __syncthreads();
  floatx4 acc[2][8];
#pragma unroll
  for (int mi = 0; mi < 2; ++mi)
#pragma unroll
    for (int ni = 0; ni < 8; ++ni) acc[mi][ni] = (floatx4){0.f, 0.f, 0.f, 0.f};
#pragma unroll
  for (int kk = 0; kk < 4; ++kk) {
    int seg = kk * 4 + l4;
    short8 a0 = *(const short8*)(&Alds[(wave * 32 + l15) * 128 + ((seg ^ l15) << 3)]);
    short8 a1 = *(const short8*)(&Alds[(wave * 32 + 16 + l15) * 128 + ((seg ^ l15) << 3)]);
#pragma unroll
    for (int ni = 0; ni < 8; ++ni) {
      short8 bfr = *(const short8*)(W0 + (ni * 16 + l15) * 128 + kk * 32 + l4 * 8);
      acc[0][ni] = __builtin_amdgcn_mfma_f32_16x16x32_bf16(a0, bfr, acc[0][ni], 0, 0, 0);
      acc[1][ni] = __builtin_amdgcn_mfma_f32_16x16x32_bf16(a1, bfr, acc[1][ni], 0, 0, 0);
    }
  }
  // S_c = sum_tau d_c^{127-tau} k[tau][c]; tau = wave*32 + mi*16 + l4*4 + j
  int T0 = wave * 32 + l4 * 4;
#pragma unroll
  for (int ni = 0; ni < 8; ++ni) {
    int c = ni * 16 + l15;
    float a = fmaxf(td[c], 0.f);
    float E = __expf(-a * (float)(127 - T0));   // d^{127-T0}
    float r1 = __expf(a);                        // d^{-1}
    float r16 = __expf(a * 16.f);
    float w = E, sum;
    sum  = w * acc[0][ni][0]; w *= r1;
    sum += w * acc[0][ni][1]; w *= r1;
    sum += w * acc[0][ni][2]; w *= r1;
    sum += w * acc[0][ni][3];
    w = E * r16;
    sum += w * acc[1][ni][0]; w *= r1;
    sum += w * acc[1][ni][1]; w *= r1;
    sum += w * acc[1][ni][2]; w *= r1;
    sum += w * acc[1][ni][3];
    sum += __shfl_xor(sum, 16);
    sum += __shfl_xor(sum, 32);
    if (l4 == 0) Sred[wave * 128 + c] = sum;
  }
  __syncthreads();
  if (tid < 128) {
    float s = Sred[tid] + Sred[128 + tid] + Sred[256 + tid] + Sred[384 + tid];
    Sbuf[(blockIdx.x & 127) * 1024 + (blockIdx.x >> 7) * 128 + tid] = s;
  }
}

// ---------------------------------------------------------------------------
// Scan phase 2: per (b,c) scan over 128 chunks; one wave, 2 chunks per lane.
__global__ __launch_bounds__(256) void scan2_kernel(const float* __restrict__ S,
                                                    const float* __restrict__ td,
                                                    float* __restrict__ init) {
  int wave = threadIdx.x >> 6, lane = threadIdx.x & 63;
  int bc = blockIdx.x * 4 + wave;   // 0..1023
  int c = bc & 127;
  float a1 = __expf(-fmaxf(td[c], 0.f) * 128.f);   // decay^CLN
  float s0 = S[(2 * lane) * 1024 + bc];
  float s1 = S[(2 * lane + 1) * 1024 + bc];
  float s = s1 + a1 * s0;   // pair-combined segment sum
  float a = a1 * a1;
  for (int off = 1; off < 64; off <<= 1) {
    float ss = __shfl_up(s, off);
    float aa = __shfl_up(a, off);
    if (lane >= off) { s = s + a * ss; a = a * aa; }
  }
  float e = __shfl_up(s, 1);          // exclusive over pairs
  if (lane == 0) e = 0.f;
  init[(2 * lane) * 1024 + bc] = e;
  init[(2 * lane + 1) * 1024 + bc] = a1 * e + s0;
}

// ---------------------------------------------------------------------------
// gemm_y2: v,r,k GEMMs + sigmoid + in-register FULL scan (init known) -> y only.
// y = sig(r)*v + sig(r)*(local_scan(k) + d^{t+1}*init[c]); bf16, coalesced.
// UNCAPPED registers (spill is far worse than 2-wave occupancy; LDS-limited anyway).
__global__ __launch_bounds__(256) void gemm_y_kernel(
    const u16* __restrict__ A, const u16* __restrict__ Wv_, const u16* __restrict__ Wr_,
    const u16* __restrict__ Wk_, const float* __restrict__ td,
    const float* __restrict__ init_, u16* __restrict__ outY) {
  __shared__ u16 Alds[128 * 128];
  __shared__ u16 Wlds[128 * 128];
  __shared__ float SWT[512];          // per-wave 32-token inclusive totals [wave][c]
  __shared__ float ILS[128];          // init[c] for this (b, chunk)
  int tid = threadIdx.x;
  int wave = tid >> 6, lane = tid & 63;
  int l15 = lane & 15, l4 = lane >> 4;
  size_t row0 = (size_t)blockIdx.x * 128;
  int bI = blockIdx.x >> 7, chunkI = blockIdx.x & 127;
  if (tid < 128) ILS[tid] = init_[chunkI * 1024 + bI * 128 + tid];

  // stage A (xn tile) + first weight (Wv)
#pragma unroll
  for (int it = 0; it < 8; ++it) {
    int idx = it * 256 + tid;
    int rr = idx >> 4, s = idx & 15;
    uint4 d = *(const uint4*)(A + (row0 + rr) * 128 + s * 8);
    *(uint4*)(&Alds[rr * 128 + ((s ^ (rr & 15)) << 3)]) = d;
  }
#pragma unroll
  for (int it = 0; it < 8; ++it) {
    int idx = it * 256 + tid;
    int rr = idx >> 4, s = idx & 15;
    uint4 d = *(const uint4*)(Wv_ + rr * 128 + s * 8);
    *(uint4*)(&Wlds[rr * 128 + ((s ^ (rr & 15)) << 3)]) = d;
  }
  // per-ni channel decay constants
  float dd[8], d4a[8];
#pragma unroll
  for (int ni = 0; ni < 8; ++ni) {
    float a = fmaxf(td[ni * 16 + l15], 0.f);
    float d = __expf(-a);
    dd[ni] = d;
    float d2 = d * d;
    d4a[ni] = d2 * d2;
  }
  __syncthreads();

  // ---- v GEMM ----
  floatx4 accv[2][8];
#pragma unroll
  for (int mi = 0; mi < 2; ++mi)
#pragma unroll
    for (int ni = 0; ni < 8; ++ni) accv[mi][ni] = (floatx4){0.f, 0.f, 0.f, 0.f};
#pragma unroll
  for (int kk = 0; kk < 4; ++kk) {
    int seg = kk * 4 + l4;
    short8 a0 = *(const short8*)(&Alds[(wave * 32 + l15) * 128 + ((seg ^ l15) << 3)]);
    short8 a1 = *(const short8*)(&Alds[(wave * 32 + 16 + l15) * 128 + ((seg ^ l15) << 3)]);
#pragma unroll
    for (int ni = 0; ni < 8; ++ni) {
      short8 bfr = *(const short8*)(&Wlds[(ni * 16 + l15) * 128 + ((seg ^ l15) << 3)]);
      accv[0][ni] = __builtin_amdgcn_mfma_f32_16x16x32_bf16(a0, bfr, accv[0][ni], 0, 0, 0);
      accv[1][ni] = __builtin_amdgcn_mfma_f32_16x16x32_bf16(a1, bfr, accv[1][ni], 0, 0, 0);
    }
  }
  __syncthreads();
  // ---- r GEMM ----
#pragma unroll
  for (int it = 0; it < 8; ++it) {
    int idx = it * 256 + tid;
    int rr = idx >> 4, s = idx & 15;
    uint4 d = *(const uint4*)(Wr_ + rr * 128 + s * 8);
    *(uint4*)(&Wlds[rr * 128 + ((s ^ (rr & 15)) << 3)]) = d;
  }
  __syncthreads();
  floatx4 accr[2][8];
#pragma unroll
  for (int mi = 0; mi < 2; ++mi)
#pragma unroll
    for (int ni = 0; ni < 8; ++ni) accr[mi][ni] = (floatx4){0.f, 0.f, 0.f, 0.f};
#pragma unroll
  for (int kk = 0; kk < 4; ++kk) {
    int seg = kk * 4 + l4;
    short8 a0 = *(const short8*)(&Alds[(wave * 32 + l15) * 128 + ((seg ^ l15) << 3)]);
    short8 a1 = *(const short8*)(&Alds[(wave * 32 + 16 + l15) * 128 + ((seg ^ l15) << 3)]);
#pragma unroll
    for (int ni = 0; ni < 8; ++ni) {
      short8 bfr = *(const short8*)(&Wlds[(ni * 16 + l15) * 128 + ((seg ^ l15) << 3)]);
      accr[0][ni] = __builtin_amdgcn_mfma_f32_16x16x32_bf16(a0, bfr, accr[0][ni], 0, 0, 0);
      accr[1][ni] = __builtin_amdgcn_mfma_f32_16x16x32_bf16(a1, bfr, accr[1][ni], 0, 0, 0);
    }
  }
  // sigmoid; pack rs and rs*v as bf16 (frees accv/accr)
  u32 rvp[2][8][2], rp[2][8][2];
#pragma unroll
  for (int mi = 0; mi < 2; ++mi) {
#pragma unroll
    for (int ni = 0; ni < 8; ++ni) {
      float rs[4], rv[4];
#pragma unroll
      for (int j = 0; j < 4; ++j) {
        float sg = 1.f / (1.f + __expf(-accr[mi][ni][j]));
        rs[j] = sg;
        rv[j] = sg * accv[mi][ni][j];
      }
      rvp[mi][ni][0] = (u32)f2bf(rv[0]) | ((u32)f2bf(rv[1]) << 16);
      rvp[mi][ni][1] = (u32)f2bf(rv[2]) | ((u32)f2bf(rv[3]) << 16);
      rp[mi][ni][0] = (u32)f2bf(rs[0]) | ((u32)f2bf(rs[1]) << 16);
      rp[mi][ni][1] = (u32)f2bf(rs[2]) | ((u32)f2bf(rs[3]) << 16);
    }
  }
  __syncthreads();
  // ---- k GEMM ----
#pragma unroll
  for (int it = 0; it < 8; ++it) {
    int idx = it * 256 + tid;
    int rr = idx >> 4, s = idx & 15;
    uint4 d = *(const uint4*)(Wk_ + rr * 128 + s * 8);
    *(uint4*)(&Wlds[rr * 128 + ((s ^ (rr & 15)) << 3)]) = d;
  }
  __syncthreads();
  floatx4 acck[2][8];
#pragma unroll
  for (int mi = 0; mi < 2; ++mi)
#pragma unroll
    for (int ni = 0; ni < 8; ++ni) acck[mi][ni] = (floatx4){0.f, 0.f, 0.f, 0.f};
#pragma unroll
  for (int kk = 0; kk < 4; ++kk) {
    int seg = kk * 4 + l4;
    short8 a0 = *(const short8*)(&Alds[(wave * 32 + l15) * 128 + ((seg ^ l15) << 3)]);
    short8 a1 = *(const short8*)(&Alds[(wave * 32 + 16 + l15) * 128 + ((seg ^ l15) << 3)]);
#pragma unroll
    for (int ni = 0; ni < 8; ++ni) {
      short8 bfr = *(const short8*)(&Wlds[(ni * 16 + l15) * 128 + ((seg ^ l15) << 3)]);
      acck[0][ni] = __builtin_amdgcn_mfma_f32_16x16x32_bf16(a0, bfr, acck[0][ni], 0, 0, 0);
      acck[1][ni] = __builtin_amdgcn_mfma_f32_16x16x32_bf16(a1, bfr, acck[1][ni], 0, 0, 0);
    }
  }
  // ---- in-register weighted prefix scan over tokens (per channel) ----
  // token t = wave*32 + mi*16 + l4*4 + j; channel c = ni*16 + l15
  float Elr[2][8];    // exclusive within 16-token mi-group (before this lane's 4)
  float B0r[8];       // mi=0 group inclusive total
#pragma unroll
  for (int ni = 0; ni < 8; ++ni) {
    float d = dd[ni], d4 = d4a[ni];
    float d8 = d4 * d4, d16 = d8 * d8;
    float I[2];
#pragma unroll
    for (int mi = 0; mi < 2; ++mi) {
      float p0 = acck[mi][ni][0];
      float p1 = d * p0 + acck[mi][ni][1];
      float p2 = d * p1 + acck[mi][ni][2];
      float p3 = d * p2 + acck[mi][ni][3];
      acck[mi][ni][0] = p0; acck[mi][ni][1] = p1;
      acck[mi][ni][2] = p2; acck[mi][ni][3] = p3;
      float Iv = p3;
      float t1 = __shfl_up(Iv, 16);
      if (l4 >= 1) Iv += d4 * t1;
      float t2 = __shfl_up(Iv, 32);
      if (l4 >= 2) Iv += d8 * t2;
      float ex = __shfl_up(Iv, 16);
      Elr[mi][ni] = (l4 == 0) ? 0.f : ex;
      I[mi] = Iv;
    }
    float B0 = __shfl(I[0], 48 + l15);
    float B1 = __shfl(I[1], 48 + l15);
    B0r[ni] = B0;
    if (l4 == 0) SWT[wave * 128 + ni * 16 + l15] = B1 + d16 * B0;
  }
  __syncthreads();
  // ---- combine (seeded with init) + y -> Wlds (reused as y staging) ----
  u16* YW = Wlds;
#pragma unroll
  for (int ni = 0; ni < 8; ++ni) {
    int c = ni * 16 + l15;
    float d = dd[ni], d4 = d4a[ni];
    float d8 = d4 * d4, d12 = d8 * d4, d16 = d8 * d8, d32 = d16 * d16;
    float e = ILS[c];                 // init enters with d^{32*wave} via the chain
#pragma unroll
    for (int wv = 0; wv < 3; ++wv)
      if (wv < wave) e = e * d32 + SWT[wv * 128 + c];
    float d4l = (l4 == 0) ? 1.f : ((l4 == 1) ? d4 : ((l4 == 2) ? d8 : d12));
#pragma unroll
    for (int mi = 0; mi < 2; ++mi) {
      float Emi = (mi == 0) ? e : (e * d16 + B0r[ni]);
      float Sb = Elr[mi][ni] + d4l * Emi;
      float w = d;   // d^{j+1}
#pragma unroll
      for (int j = 0; j < 4; ++j) {
        float s = acck[mi][ni][j] + w * Sb;
        w *= d;
        float rvv = bf2f((u16)(rvp[mi][ni][j >> 1] >> ((j & 1) * 16)));
        float rss = bf2f((u16)(rp[mi][ni][j >> 1] >> ((j & 1) * 16)));
        float y = rvv + rss * s;
        int row = wave * 32 + mi * 16 + l4 * 4 + j;
        int colsw = c ^ (((row >> 2) & 3) << 4);
        YW[row * 128 + colsw] = f2bf(y);
      }
    }
  }
  __syncthreads();
  // coalesced y store
#pragma unroll
  for (int it = 0; it < 8; ++it) {
    int idx = it * 256 + tid;
    int row = idx >> 4, cb = (idx & 15) * 8;
    int csw = cb ^ (((row >> 2) & 3) << 4);
    uint4 dv = *(const uint4*)(&YW[row * 128 + csw]);
    *(uint4*)(outY + (row0 + row) * 128 + cb) = dv;
  }
}

// ---------------------------------------------------------------------------
// Tail v5: Y staged (pure swizzled copy) -> t = Wo·y^T -> T2 -> g/bt GEMMs ->
// out = out*(1+tanh(g)) + bt. 32 KB LDS, 512 thr.
__global__ __launch_bounds__(512, 4) void tail_kernel(
    const u16* __restrict__ yl,
    const u16* __restrict__ Wo, const u16* __restrict__ Wg, const u16* __restrict__ Wb,
    const float* __restrict__ gpb, const float* __restrict__ bpb,
    float* __restrict__ outp) {
  __shared__ u32 SMEM[8192];          // 32 KB: Y -> T2 -> MB
  u16* Y = (u16*)SMEM;
  u16* T2 = (u16*)SMEM;
  u32* MB = SMEM;

  int tid = threadIdx.x;
  int wave = tid >> 6, lane = tid & 63;
  int l15 = lane & 15, l4 = lane >> 4;
  int b = blockIdx.x >> 7;
  int chunk = blockIdx.x & 127;
  size_t ebase = ((size_t)b * 16384 + (size_t)chunk * 128) * 128;

  // ---- Y stage: swizzled copy ----
#pragma unroll
  for (int it = 0; it < 4; ++it) {
    int idx = it * 512 + tid;         // 0..2047
    int t = idx >> 4;
    int c8 = (idx & 15) * 8;
    uint4 yv = *(const uint4*)(yl + ebase + (size_t)t * 128 + c8);
    *(uint4*)(&Y[t * 128 + (((c8 >> 3) ^ (t & 15)) << 3)]) = yv;
  }
  __syncthreads();

  // ---- GEMM1: t[o][tok] = Wo(16 rows/wave) · Y^T ----
  int ob = wave * 16;
  short8 wof[4];
#pragma unroll
  for (int kk = 0; kk < 4; ++kk)
    wof[kk] = *(const short8*)(Wo + (ob + l15) * 128 + kk * 32 + l4 * 8);
  floatx4 acc[8];
#pragma unroll
  for (int ni = 0; ni < 8; ++ni) acc[ni] = (floatx4){0.f, 0.f, 0.f, 0.f};
#pragma unroll
  for (int kk = 0; kk < 4; ++kk) {
    int seg = kk * 4 + l4;
#pragma unroll
    for (int ni = 0; ni < 8; ++ni) {
      short8 yf = *(const short8*)(&Y[(ni * 16 + l15) * 128 + ((seg ^ l15) << 3)]);
      acc[ni] = __builtin_amdgcn_mfma_f32_16x16x32_bf16(wof[kk], yf, acc[ni], 0, 0, 0);
    }
  }
  __syncthreads();   // all Y reads complete before overwrite

  // write T2 [tok][o] bf16, swizzled, packed o-pairs
#pragma unroll
  for (int ni = 0; ni < 8; ++ni) {
    int tok = ni * 16 + l15;
#pragma unroll
    for (int j = 0; j < 4; j += 2) {
      int o = ob + l4 * 4 + j;
      u32 pack = (u32)f2bf(acc[ni][j]) | ((u32)f2bf(acc[ni][j + 1]) << 16);
      int pos = tok * 128 + ((((o >> 3) ^ (tok & 15)) << 3) | (o & 7));
      *(u32*)(T2 + pos) = pack;
    }
  }
  __syncthreads();

  // ---- GEMM2: g/bt [o'][tok] over K=o ----
  short8 wgf[4], wbf2[4];
#pragma unroll
  for (int kk = 0; kk < 4; ++kk) {
    wgf[kk]  = *(const short8*)(Wg + (ob + l15) * 128 + kk * 32 + l4 * 8);
    wbf2[kk] = *(const short8*)(Wb + (ob + l15) * 128 + kk * 32 + l4 * 8);
  }
  floatx4 ag[8], ab[8];
#pragma unroll
  for (int ni = 0; ni < 8; ++ni) {
    ag[ni] = (floatx4){0.f, 0.f, 0.f, 0.f};
    ab[ni] = (floatx4){0.f, 0.f, 0.f, 0.f};
  }
#pragma unroll
  for (int kk = 0; kk < 4; ++kk) {
    int seg = kk * 4 + l4;
#pragma unroll
    for (int ni = 0; ni < 8; ++ni) {
      short8 tf = *(const short8*)(&T2[(ni * 16 + l15) * 128 + ((seg ^ l15) << 3)]);
      ag[ni] = __builtin_amdgcn_mfma_f32_16x16x32_bf16(wgf[kk], tf, ag[ni], 0, 0, 0);
      ab[ni] = __builtin_amdgcn_mfma_f32_16x16x32_bf16(wbf2[kk], tf, ab[ni], 0, 0, 0);
    }
  }
  __syncthreads();   // T2 fully consumed

  // ---- Epilogue in two o-halves of 64 (MB = 32 KB) ----
#pragma unroll
  for (int h = 0; h < 2; ++h) {
    if ((wave >> 2) == h) {
      int orel0 = (wave & 3) * 16;
#pragma unroll
      for (int ni = 0; ni < 8; ++ni) {
        int tok = ni * 16 + l15;
#pragma unroll
        for (int j = 0; j < 4; ++j) {
          int orel = orel0 + l4 * 4 + j;
          int o = h * 64 + orel;
          float g = ag[ni][j] + gpb[o];
          float t1 = __expf(2.f * g);
          float m = 2.f - 2.f / (t1 + 1.f);          // 1 + tanh(g), inf-safe
          float bt = ab[ni][j] + bpb[o];
          int rot = ((orel & 3) << 2) | ((orel >> 2) & 3);
          MB[orel * 128 + ((((tok >> 3) ^ rot) << 3) | (tok & 7))] =
              (u32)f2bf(m) | ((u32)f2bf(bt) << 16);
        }
      }
    }
    __syncthreads();
#pragma unroll
    for (int it = 0; it < 2; ++it) {
      int idx = it * 512 + tid;
      int orel = idx >> 4, seg = idx & 15;
      int o = h * 64 + orel;
      int rot = ((orel & 3) << 2) | ((orel >> 2) & 3);
      int sp = ((seg ^ rot) << 3);
      uint4 mb0 = *(const uint4*)(&MB[orel * 128 + sp]);
      uint4 mb1 = *(const uint4*)(&MB[orel * 128 + sp + 4]);
      float* op = outp + ((size_t)(b * 128 + o)) * 16384 + chunk * 128 + seg * 8;
      float4 o0 = *(float4*)op;
      float4 o1 = *(float4*)(op + 4);
      o0.x = o0.x * bf2f((u16)(mb0.x & 0xffff)) + bf2f((u16)(mb0.x >> 16));
      o0.y = o0.y * bf2f((u16)(mb0.y & 0xffff)) + bf2f((u16)(mb0.y >> 16));
      o0.z = o0.z * bf2f((u16)(mb0.z & 0xffff)) + bf2f((u16)(mb0.z >> 16));
      o0.w = o0.w * bf2f((u16)(mb0.w & 0xffff)) + bf2f((u16)(mb0.w >> 16));
      o1.x = o1.x * bf2f((u16)(mb1.x & 0xffff)) + bf2f((u16)(mb1.x >> 16));
      o1.y = o1.y * bf2f((u16)(mb1.y & 0xffff)) + bf2f((u16)(mb1.y >> 16));
      o1.z = o1.z * bf2f((u16)(mb1.z & 0xffff)) + bf2f((u16)(mb1.z >> 16));
      o1.w = o1.w * bf2f((u16)(mb1.w & 0xffff)) + bf2f((u16)(mb1.w >> 16));
      *(float4*)op = o0;
      *(float4*)(op + 4) = o1;
    }
    __syncthreads();
  }
}

// ---------------------------------------------------------------------------
extern "C" void kernel_launch(void* const* d_in, const int* in_sizes, int n_in,
                              void* d_out, int out_size, void* d_ws, size_t ws_size,
                              hipStream_t stream) {
  const float* x        = (const float*)d_in[0];
  const float* gs       = (const float*)d_in[1];
  const float* cond_gw  = (const float*)d_in[2];
  const float* cond_gb  = (const float*)d_in[3];
  const float* cond_bw  = (const float*)d_in[4];
  const float* cond_bb  = (const float*)d_in[5];
  const float* td       = (const float*)d_in[6];
  const float* Wk       = (const float*)d_in[7];
  const float* Wv       = (const float*)d_in[8];
  const float* Wr       = (const float*)d_in[9];
  const float* Wo       = (const float*)d_in[10];
  const float* ln_g     = (const float*)d_in[11];
  const float* ln_b     = (const float*)d_in[12];
  const float* gp_w     = (const float*)d_in[13];
  const float* gp_b     = (const float*)d_in[14];
  const float* bp_w     = (const float*)d_in[15];
  const float* bp_b     = (const float*)d_in[16];
  float* outp = (float*)d_out;

  char* w = (char*)d_ws;
  float* gamma = (float*)w; w += 4096;
  float* beta  = (float*)w; w += 4096;
  u16* wbf     = (u16*)w;   w += 6 * 2 * 16384 * sizeof(u16);     // 384 KB
  u16* xn      = (u16*)w;   w += (size_t)MM * 128 * sizeof(u16);  // 32 MB
  u16* ybuf    = (u16*)w;   w += (size_t)MM * 128 * sizeof(u16);  // 32 MB
  float* Sbuf  = (float*)w; w += NCH * 1024 * sizeof(float);      // 512 KB
  float* ibuf  = (float*)w; w += NCH * 1024 * sizeof(float);      // 512 KB

  film_kernel<<<4, 256, 0, stream>>>(gs, cond_gw, cond_gb, cond_bw, cond_bb, gamma, beta);
  convert_kernel<<<768, 256, 0, stream>>>(Wk, Wv, Wr, Wo, gp_w, bp_w, wbf);

  for (int blk = 0; blk < 2; ++blk) {
    const u16* bWk = wbf + 0 * 32768 + blk * 16384;
    const u16* bWv = wbf + 1 * 32768 + blk * 16384;
    const u16* bWr = wbf + 2 * 32768 + blk * 16384;
    const u16* bWo = wbf + 3 * 32768 + blk * 16384;
    const u16* bGp = wbf + 4 * 32768 + blk * 16384;
    const u16* bBp = wbf + 5 * 32768 + blk * 16384;
    const float* tdi = td + blk * 128;

    if (blk == 0)
      prep_kernel<1><<<2048, 256, 0, stream>>>(x, gamma, beta, ln_g, ln_b, outp, xn);
    else
      prep_kernel<0><<<2048, 256, 0, stream>>>(outp, nullptr, nullptr, ln_g + 128,
                                               ln_b + 128, nullptr, xn);

    gemm_S_kernel<<<1024, 256, 0, stream>>>(xn, bWk, tdi, Sbuf);
    scan2_kernel<<<256, 256, 0, stream>>>(Sbuf, tdi, ibuf);
    gemm_y_kernel<<<1024, 256, 0, stream>>>(xn, bWv, bWr, bWk, tdi, ibuf, ybuf);
    tail_kernel<<<1024, 512, 0, stream>>>(ybuf, bWo, bGp, bBp,
                                          gp_b + blk * 128, bp_b + blk * 128, outp);
  }
}

// Round 10
// 309.606 us; speedup vs baseline: 1.0353x; 1.0353x over previous
//
#include <hip/hip_runtime.h>
#include <hip/hip_bf16.h>

// Problem constants
#define BB 8
#define CC 128
#define NN 16384            // 128*128 tokens per batch
#define MM (BB * NN)        // 131072
#define NCH 256             // scan chunks per batch-row (64 tokens each)
#define CLN 64              // chunk length

typedef __attribute__((ext_vector_type(8))) short short8;   // 8 x bf16 (4 VGPRs)
typedef __attribute__((ext_vector_type(4))) float floatx4;  // MFMA accumulator
typedef unsigned short u16;
typedef unsigned int u32;

__device__ __forceinline__ float bf2f(u16 h) {
  u32 u = ((u32)h) << 16;
  return __builtin_bit_cast(float, u);
}
__device__ __forceinline__ u16 f2bf(float f) {
  u32 u = __builtin_bit_cast(u32, f);
  u32 r = u + 0x7FFFu + ((u >> 16) & 1u);   // round-to-nearest-even
  return (u16)(r >> 16);
}

// ---------------------------------------------------------------------------
// FiLM params: gamma[b,c] = gs[b,:]·cond_gw[c,:] + cond_gb[c]; beta likewise.
__global__ void film_kernel(const float* __restrict__ gs, const float* __restrict__ gw,
                            const float* __restrict__ gb, const float* __restrict__ bw,
                            const float* __restrict__ bb, float* __restrict__ gamma,
                            float* __restrict__ beta) {
  int idx = blockIdx.x * 256 + threadIdx.x;   // 0..1023
  int b = idx >> 7, c = idx & 127;
  float sg = 0.f, sb = 0.f;
  for (int j = 0; j < 128; ++j) {
    float g = gs[b * 128 + j];
    sg += g * gw[c * 128 + j];
    sb += g * bw[c * 128 + j];
  }
  gamma[idx] = sg + gb[c];
  beta[idx] = sb + bb[c];
}

// ---------------------------------------------------------------------------
// Convert all 6 weight tensors (each (2,128,128) f32) to bf16, packed
// [which][block][o][c] at dst + which*32768.
__global__ void convert_kernel(const float* __restrict__ Wk, const float* __restrict__ Wv,
                               const float* __restrict__ Wr, const float* __restrict__ Wo,
                               const float* __restrict__ gp, const float* __restrict__ bp,
                               u16* __restrict__ dst) {
  int idx = blockIdx.x * 256 + threadIdx.x;   // 0..196607
  int which = idx >> 15;
  int off = idx & 32767;
  const float* s;
  switch (which) {
    case 0: s = Wk; break; case 1: s = Wv; break; case 2: s = Wr; break;
    case 3: s = Wo; break; case 4: s = gp; break; default: s = bp; break;
  }
  dst[idx] = f2bf(s[off]);
}

// ---------------------------------------------------------------------------
// Prep: (UPS=1) bilinear 2x upsample + write x_up to out(BCHW) + FiLM + LN -> xn bf16
//       (UPS=0) read out(BCHW) + LN -> xn bf16
template <int UPS>
__global__ __launch_bounds__(256) void prep_kernel(
    const float* __restrict__ src, const float* __restrict__ gamma,
    const float* __restrict__ beta, const float* __restrict__ lng,
    const float* __restrict__ lnb, float* __restrict__ outp, u16* __restrict__ xn) {
  __shared__ float tile[64][129];
  __shared__ float smu[64], srs[64];
  int bidx = blockIdx.x;              // 0..2047
  int half = bidx & 1;
  int ho = (bidx >> 1) & 127;
  int b = bidx >> 8;
  int wo0 = half * 64;
  int tid = threadIdx.x;
  int tk = tid & 63;
  int wo = wo0 + tk;
  int c0 = tid >> 6;                  // 0..3
  int j0 = 0, j1 = 0, i0 = 0, i1 = 0;
  float wy0 = 0.f, wy1 = 0.f, wx0 = 0.f, wx1 = 0.f;
  if (UPS) {
    int jj = ho >> 1;
    if ((ho & 1) == 0) { j0 = jj > 0 ? jj - 1 : 0; j1 = jj; wy0 = 0.25f; wy1 = 0.75f; }
    else               { j0 = jj; j1 = jj < 63 ? jj + 1 : 63; wy0 = 0.75f; wy1 = 0.25f; }
    int ii = wo >> 1;
    if ((wo & 1) == 0) { i0 = ii > 0 ? ii - 1 : 0; i1 = ii; wx0 = 0.25f; wx1 = 0.75f; }
    else               { i0 = ii; i1 = ii < 63 ? ii + 1 : 63; wx0 = 0.75f; wx1 = 0.25f; }
  }
  for (int it = 0; it < 32; ++it) {
    int c = it * 4 + c0;
    float v;
    if (UPS) {
      const float* xp = src + ((size_t)(b * 128 + c)) * 4096;
      v = wy0 * (wx0 * xp[j0 * 64 + i0] + wx1 * xp[j0 * 64 + i1]) +
          wy1 * (wx0 * xp[j1 * 64 + i0] + wx1 * xp[j1 * 64 + i1]);
      outp[((size_t)(b * 128 + c)) * 16384 + ho * 128 + wo] = v;
      v = v * (1.f + gamma[b * 128 + c]) + beta[b * 128 + c];
    } else {
      v = src[((size_t)(b * 128 + c)) * 16384 + ho * 128 + wo];
    }
    tile[tk][c] = v;
  }
  __syncthreads();
  {
    int token = tid >> 2, q = tid & 3;
    float s = 0.f, s2 = 0.f;
    for (int j = 0; j < 32; ++j) { float v = tile[token][q * 32 + j]; s += v; s2 += v * v; }
    s += __shfl_xor(s, 1); s2 += __shfl_xor(s2, 1);
    s += __shfl_xor(s, 2); s2 += __shfl_xor(s2, 2);
    if (q == 0) {
      float mu = s * 0.0078125f;
      float var = s2 * 0.0078125f - mu * mu;
      smu[token] = mu;
      srs[token] = rsqrtf(var + 1e-5f);
    }
  }
  __syncthreads();
  size_t base = ((size_t)b * 16384 + ho * 128 + wo0) * 128;
  for (int it = 0; it < 32; ++it) {
    int idx = it * 256 + tid;
    int token = idx >> 7, c = idx & 127;
    float v = (tile[token][c] - smu[token]) * srs[token] * lng[c] + lnb[c];
    xn[base + idx] = f2bf(v);
  }
}

// ---------------------------------------------------------------------------
// gemm_S: k-GEMM (staged weights), fused decay-weighted sums for TWO 64-token
// halves -> Sbuf (chunk granularity = 64 tokens).
__global__ __launch_bounds__(256) void gemm_S_kernel(
    const u16* __restrict__ A, const u16* __restrict__ W0,
    const float* __restrict__ td, float* __restrict__ Sbuf) {
  __shared__ u16 Alds[128 * 128];
  __shared__ u16 Wlds[128 * 128];
  __shared__ float Sred[512];         // [wave][c]
  int tid = threadIdx.x;
  int wave = tid >> 6, lane = tid & 63;
  int l15 = lane & 15, l4 = lane >> 4;
  size_t row0 = (size_t)blockIdx.x * 128;
#pragma unroll
  for (int it = 0; it < 8; ++it) {
    int idx = it * 256 + tid;
    int rr = idx >> 4, s = idx & 15;
    uint4 d = *(const uint4*)(A + (row0 + rr) * 128 + s * 8);
    *(uint4*)(&Alds[rr * 128 + ((s ^ (rr & 15)) << 3)]) = d;
  }
#pragma unroll
  for (int it = 0; it < 8; ++it) {
    int idx = it * 256 + tid;
    int rr = idx >> 4, s = idx & 15;
    uint4 d = *(const uint4*)(W0 + rr * 128 + s * 8);
    *(uint4*)(&Wlds[rr * 128 + ((s ^ (rr & 15)) << 3)]) = d;
  }
  __syncthreads();
  floatx4 acc[2][8];
#pragma unroll
  for (int mi = 0; mi < 2; ++mi)
#pragma unroll
    for (int ni = 0; ni < 8; ++ni) acc[mi][ni] = (floatx4){0.f, 0.f, 0.f, 0.f};
#pragma unroll
  for (int kk = 0; kk < 4; ++kk) {
    int seg = kk * 4 + l4;
    short8 a0 = *(const short8*)(&Alds[(wave * 32 + l15) * 128 + ((seg ^ l15) << 3)]);
    short8 a1 = *(const short8*)(&Alds[(wave * 32 + 16 + l15) * 128 + ((seg ^ l15) << 3)]);
#pragma unroll
    for (int ni = 0; ni < 8; ++ni) {
      short8 bfr = *(const short8*)(&Wlds[(ni * 16 + l15) * 128 + ((seg ^ l15) << 3)]);
      acc[0][ni] = __builtin_amdgcn_mfma_f32_16x16x32_bf16(a0, bfr, acc[0][ni], 0, 0, 0);
      acc[1][ni] = __builtin_amdgcn_mfma_f32_16x16x32_bf16(a1, bfr, acc[1][ni], 0, 0, 0);
    }
  }
  // Half-local S: token t_loc = (wave&1)*32 + mi*16 + l4*4 + j; weight d^{63-t_loc}
  int T0h = (wave & 1) * 32 + l4 * 4;
#pragma unroll
  for (int ni = 0; ni < 8; ++ni) {
    int c = ni * 16 + l15;
    float a = fmaxf(td[c], 0.f);
    float E = __expf(-a * (float)(63 - T0h));   // d^{63-T0h}
    float r1 = __expf(a);                        // d^{-1}
    float r16 = __expf(a * 16.f);
    float w = E, sum;
    sum  = w * acc[0][ni][0]; w *= r1;
    sum += w * acc[0][ni][1]; w *= r1;
    sum += w * acc[0][ni][2]; w *= r1;
    sum += w * acc[0][ni][3];
    w = E * r16;
    sum += w * acc[1][ni][0]; w *= r1;
    sum += w * acc[1][ni][1]; w *= r1;
    sum += w * acc[1][ni][2]; w *= r1;
    sum += w * acc[1][ni][3];
    sum += __shfl_xor(sum, 16);
    sum += __shfl_xor(sum, 32);
    if (l4 == 0) Sred[wave * 128 + c] = sum;
  }
  __syncthreads();
  if (tid < 128) {
    int hc0 = (blockIdx.x & 127) * 2;
    int bo = (blockIdx.x >> 7) * 128 + tid;
    Sbuf[(size_t)hc0 * 1024 + bo]       = Sred[tid] + Sred[128 + tid];
    Sbuf[(size_t)(hc0 + 1) * 1024 + bo] = Sred[256 + tid] + Sred[384 + tid];
  }
}

// ---------------------------------------------------------------------------
// Scan phase 2: per (b,c) scan over 256 chunks of 64 tokens; one wave, 4/lane.
__global__ __launch_bounds__(256) void scan2_kernel(const float* __restrict__ S,
                                                    const float* __restrict__ td,
                                                    float* __restrict__ init) {
  int wave = threadIdx.x >> 6, lane = threadIdx.x & 63;
  int bc = blockIdx.x * 4 + wave;   // 0..1023
  int c = bc & 127;
  float a1 = __expf(-fmaxf(td[c], 0.f) * 64.f);   // decay^CLN
  float s0 = S[(size_t)(4 * lane + 0) * 1024 + bc];
  float s1 = S[(size_t)(4 * lane + 1) * 1024 + bc];
  float s2 = S[(size_t)(4 * lane + 2) * 1024 + bc];
  float s3 = S[(size_t)(4 * lane + 3) * 1024 + bc];
  float a2 = a1 * a1;
  float T = s3 + a1 * s2 + a2 * (s1 + a1 * s0);   // 4-seg combined
  float s = T, a = a2 * a2;                        // carry d^256
  for (int off = 1; off < 64; off <<= 1) {
    float ss = __shfl_up(s, off);
    float aa = __shfl_up(a, off);
    if (lane >= off) { s = s + a * ss; a = a * aa; }
  }
  float e = __shfl_up(s, 1);          // exclusive over 4-groups
  if (lane == 0) e = 0.f;
  init[(size_t)(4 * lane + 0) * 1024 + bc] = e;
  float e1 = a1 * e + s0;  init[(size_t)(4 * lane + 1) * 1024 + bc] = e1;
  float e2 = a1 * e1 + s1; init[(size_t)(4 * lane + 2) * 1024 + bc] = e2;
  float e3 = a1 * e2 + s2; init[(size_t)(4 * lane + 3) * 1024 + bc] = e3;
}

// ---------------------------------------------------------------------------
// gemm_y v3: M=64 tokens/block, each wave owns a 32-channel N-slice (weights in
// registers, tail-style). k GEMM -> in-wave scan (seeded with init) -> r GEMM
// (sigmoid, packed) -> v GEMM -> y. 17 KB LDS, <=128 VGPR -> 16 waves/CU.
__global__ __launch_bounds__(256, 4) void gemm_y_kernel(
    const u16* __restrict__ xn, const u16* __restrict__ Wv_,
    const u16* __restrict__ Wr_, const u16* __restrict__ Wk_,
    const float* __restrict__ td, const float* __restrict__ init_,
    u16* __restrict__ outY) {
  __shared__ u16 Alds[64 * 128];      // 16 KB: xn half-tile -> later YW
  __shared__ float ILS[128];
  int tid = threadIdx.x;
  int wave = tid >> 6, lane = tid & 63;
  int l15 = lane & 15, l4 = lane >> 4;
  size_t row0 = (size_t)blockIdx.x * 64;
  int bI = blockIdx.x >> 8, hcI = blockIdx.x & 255;
  if (tid < 128) ILS[tid] = init_[(size_t)hcI * 1024 + bI * 128 + tid];
#pragma unroll
  for (int it = 0; it < 4; ++it) {
    int idx = it * 256 + tid;
    int rr = idx >> 4, s = idx & 15;
    uint4 d = *(const uint4*)(xn + (row0 + rr) * 128 + s * 8);
    *(uint4*)(&Alds[rr * 128 + ((s ^ (rr & 15)) << 3)]) = d;
  }
  int ob = wave * 32;
  float dd[2], d4a[2];
#pragma unroll
  for (int ni = 0; ni < 2; ++ni) {
    float a = fmaxf(td[ob + ni * 16 + l15], 0.f);
    float d = __expf(-a);
    dd[ni] = d;
    d4a[ni] = d * d * d * d;
  }
  __syncthreads();

  // ---- k GEMM (per-wave weight slice in regs) ----
  floatx4 acc[4][2];
#pragma unroll
  for (int mi = 0; mi < 4; ++mi)
#pragma unroll
    for (int ni = 0; ni < 2; ++ni) acc[mi][ni] = (floatx4){0.f, 0.f, 0.f, 0.f};
#pragma unroll
  for (int kk = 0; kk < 4; ++kk) {
    short8 w0 = *(const short8*)(Wk_ + (ob + l15) * 128 + kk * 32 + l4 * 8);
    short8 w1 = *(const short8*)(Wk_ + (ob + 16 + l15) * 128 + kk * 32 + l4 * 8);
#pragma unroll
    for (int mi = 0; mi < 4; ++mi) {
      short8 af = *(const short8*)(&Alds[(mi * 16 + l15) * 128 + (((kk * 4 + l4) ^ l15) << 3)]);
      acc[mi][0] = __builtin_amdgcn_mfma_f32_16x16x32_bf16(af, w0, acc[mi][0], 0, 0, 0);
      acc[mi][1] = __builtin_amdgcn_mfma_f32_16x16x32_bf16(af, w1, acc[mi][1], 0, 0, 0);
    }
  }

  // ---- in-wave weighted prefix scan (token = mi*16 + l4*4 + j) ----
  u32 sp[4][2][2];                    // s packed bf16
  {
    float Elr[4][2], Bm[4][2];
#pragma unroll
    for (int ni = 0; ni < 2; ++ni) {
      float d = dd[ni], d4 = d4a[ni];
      float d8 = d4 * d4;
#pragma unroll
      for (int mi = 0; mi < 4; ++mi) {
        float p0 = acc[mi][ni][0];
        float p1 = d * p0 + acc[mi][ni][1];
        float p2 = d * p1 + acc[mi][ni][2];
        float p3 = d * p2 + acc[mi][ni][3];
        acc[mi][ni][0] = p0; acc[mi][ni][1] = p1;
        acc[mi][ni][2] = p2; acc[mi][ni][3] = p3;
        float Iv = p3;
        float t1 = __shfl_up(Iv, 16);
        if (l4 >= 1) Iv += d4 * t1;
        float t2 = __shfl_up(Iv, 32);
        if (l4 >= 2) Iv += d8 * t2;
        float ex = __shfl_up(Iv, 16);
        Elr[mi][ni] = (l4 == 0) ? 0.f : ex;
        Bm[mi][ni] = __shfl(Iv, 48 + l15);
      }
    }
#pragma unroll
    for (int ni = 0; ni < 2; ++ni) {
      float d = dd[ni], d4 = d4a[ni];
      float d8 = d4 * d4, d12 = d8 * d4, d16 = d8 * d8;
      float d4l = (l4 == 0) ? 1.f : ((l4 == 1) ? d4 : ((l4 == 2) ? d8 : d12));
      float e = ILS[ob + ni * 16 + l15];
#pragma unroll
      for (int mi = 0; mi < 4; ++mi) {
        float Sb = Elr[mi][ni] + d4l * e;
        float w = d;
        float s0 = acc[mi][ni][0] + w * Sb; w *= d;
        float s1 = acc[mi][ni][1] + w * Sb; w *= d;
        float s2 = acc[mi][ni][2] + w * Sb; w *= d;
        float s3 = acc[mi][ni][3] + w * Sb;
        sp[mi][ni][0] = (u32)f2bf(s0) | ((u32)f2bf(s1) << 16);
        sp[mi][ni][1] = (u32)f2bf(s2) | ((u32)f2bf(s3) << 16);
        e = e * d16 + Bm[mi][ni];
      }
    }
  }

  // ---- r GEMM -> sigmoid packed ----
  u32 rp[4][2][2];
  {
#pragma unroll
    for (int mi = 0; mi < 4; ++mi)
#pragma unroll
      for (int ni = 0; ni < 2; ++ni) acc[mi][ni] = (floatx4){0.f, 0.f, 0.f, 0.f};
#pragma unroll
    for (int kk = 0; kk < 4; ++kk) {
      short8 w0 = *(const short8*)(Wr_ + (ob + l15) * 128 + kk * 32 + l4 * 8);
      short8 w1 = *(const short8*)(Wr_ + (ob + 16 + l15) * 128 + kk * 32 + l4 * 8);
#pragma unroll
      for (int mi = 0; mi < 4; ++mi) {
        short8 af = *(const short8*)(&Alds[(mi * 16 + l15) * 128 + (((kk * 4 + l4) ^ l15) << 3)]);
        acc[mi][0] = __builtin_amdgcn_mfma_f32_16x16x32_bf16(af, w0, acc[mi][0], 0, 0, 0);
        acc[mi][1] = __builtin_amdgcn_mfma_f32_16x16x32_bf16(af, w1, acc[mi][1], 0, 0, 0);
      }
    }
#pragma unroll
    for (int mi = 0; mi < 4; ++mi)
#pragma unroll
      for (int ni = 0; ni < 2; ++ni) {
        float r0 = 1.f / (1.f + __expf(-acc[mi][ni][0]));
        float r1 = 1.f / (1.f + __expf(-acc[mi][ni][1]));
        float r2 = 1.f / (1.f + __expf(-acc[mi][ni][2]));
        float r3 = 1.f / (1.f + __expf(-acc[mi][ni][3]));
        rp[mi][ni][0] = (u32)f2bf(r0) | ((u32)f2bf(r1) << 16);
        rp[mi][ni][1] = (u32)f2bf(r2) | ((u32)f2bf(r3) << 16);
      }
  }

  // ---- v GEMM ----
#pragma unroll
  for (int mi = 0; mi < 4; ++mi)
#pragma unroll
    for (int ni = 0; ni < 2; ++ni) acc[mi][ni] = (floatx4){0.f, 0.f, 0.f, 0.f};
#pragma unroll
  for (int kk = 0; kk < 4; ++kk) {
    short8 w0 = *(const short8*)(Wv_ + (ob + l15) * 128 + kk * 32 + l4 * 8);
    short8 w1 = *(const short8*)(Wv_ + (ob + 16 + l15) * 128 + kk * 32 + l4 * 8);
#pragma unroll
    for (int mi = 0; mi < 4; ++mi) {
      short8 af = *(const short8*)(&Alds[(mi * 16 + l15) * 128 + (((kk * 4 + l4) ^ l15) << 3)]);
      acc[mi][0] = __builtin_amdgcn_mfma_f32_16x16x32_bf16(af, w0, acc[mi][0], 0, 0, 0);
      acc[mi][1] = __builtin_amdgcn_mfma_f32_16x16x32_bf16(af, w1, acc[mi][1], 0, 0, 0);
    }
  }
  __syncthreads();   // all Alds reads done before YW overwrite

  // ---- y = sig(r)*(s + v) -> YW (= Alds region), then coalesced store ----
  u16* YW = Alds;
#pragma unroll
  for (int mi = 0; mi < 4; ++mi)
#pragma unroll
    for (int ni = 0; ni < 2; ++ni) {
      int c = ob + ni * 16 + l15;
#pragma unroll
      for (int j = 0; j < 4; ++j) {
        float s = bf2f((u16)(sp[mi][ni][j >> 1] >> ((j & 1) * 16)));
        float rs = bf2f((u16)(rp[mi][ni][j >> 1] >> ((j & 1) * 16)));
        float y = rs * (s + acc[mi][ni][j]);
        int row = mi * 16 + l4 * 4 + j;
        int colsw = c ^ (((row >> 2) & 3) << 4);
        YW[row * 128 + colsw] = f2bf(y);
      }
    }
  __syncthreads();
#pragma unroll
  for (int it = 0; it < 4; ++it) {
    int idx = it * 256 + tid;
    int row = idx >> 4, cb = (idx & 15) * 8;
    int csw = cb ^ (((row >> 2) & 3) << 4);
    uint4 dv = *(const uint4*)(&YW[row * 128 + csw]);
    *(uint4*)(outY + (row0 + row) * 128 + cb) = dv;
  }
}

// ---------------------------------------------------------------------------
// Tail v5: Y staged (pure swizzled copy) -> t = Wo·y^T -> T2 -> g/bt GEMMs ->
// out = out*(1+tanh(g)) + bt. 32 KB LDS, 512 thr.
__global__ __launch_bounds__(512, 4) void tail_kernel(
    const u16* __restrict__ yl,
    const u16* __restrict__ Wo, const u16* __restrict__ Wg, const u16* __restrict__ Wb,
    const float* __restrict__ gpb, const float* __restrict__ bpb,
    float* __restrict__ outp) {
  __shared__ u32 SMEM[8192];          // 32 KB: Y -> T2 -> MB
  u16* Y = (u16*)SMEM;
  u16* T2 = (u16*)SMEM;
  u32* MB = SMEM;

  int tid = threadIdx.x;
  int wave = tid >> 6, lane = tid & 63;
  int l15 = lane & 15, l4 = lane >> 4;
  int b = blockIdx.x >> 7;
  int chunk = blockIdx.x & 127;
  size_t ebase = ((size_t)b * 16384 + (size_t)chunk * 128) * 128;

  // ---- Y stage: swizzled copy ----
#pragma unroll
  for (int it = 0; it < 4; ++it) {
    int idx = it * 512 + tid;         // 0..2047
    int t = idx >> 4;
    int c8 = (idx & 15) * 8;
    uint4 yv = *(const uint4*)(yl + ebase + (size_t)t * 128 + c8);
    *(uint4*)(&Y[t * 128 + (((c8 >> 3) ^ (t & 15)) << 3)]) = yv;
  }
  __syncthreads();

  // ---- GEMM1: t[o][tok] = Wo(16 rows/wave) · Y^T ----
  int ob = wave * 16;
  short8 wof[4];
#pragma unroll
  for (int kk = 0; kk < 4; ++kk)
    wof[kk] = *(const short8*)(Wo + (ob + l15) * 128 + kk * 32 + l4 * 8);
  floatx4 acc[8];
#pragma unroll
  for (int ni = 0; ni < 8; ++ni) acc[ni] = (floatx4){0.f, 0.f, 0.f, 0.f};
#pragma unroll
  for (int kk = 0; kk < 4; ++kk) {
    int seg = kk * 4 + l4;
#pragma unroll
    for (int ni = 0; ni < 8; ++ni) {
      short8 yf = *(const short8*)(&Y[(ni * 16 + l15) * 128 + ((seg ^ l15) << 3)]);
      acc[ni] = __builtin_amdgcn_mfma_f32_16x16x32_bf16(wof[kk], yf, acc[ni], 0, 0, 0);
    }
  }
  __syncthreads();   // all Y reads complete before overwrite

  // write T2 [tok][o] bf16, swizzled, packed o-pairs
#pragma unroll
  for (int ni = 0; ni < 8; ++ni) {
    int tok = ni * 16 + l15;
#pragma unroll
    for (int j = 0; j < 4; j += 2) {
      int o = ob + l4 * 4 + j;
      u32 pack = (u32)f2bf(acc[ni][j]) | ((u32)f2bf(acc[ni][j + 1]) << 16);
      int pos = tok * 128 + ((((o >> 3) ^ (tok & 15)) << 3) | (o & 7));
      *(u32*)(T2 + pos) = pack;
    }
  }
  __syncthreads();

  // ---- GEMM2: g/bt [o'][tok] over K=o ----
  short8 wgf[4], wbf2[4];
#pragma unroll
  for (int kk = 0; kk < 4; ++kk) {
    wgf[kk]  = *(const short8*)(Wg + (ob + l15) * 128 + kk * 32 + l4 * 8);
    wbf2[kk] = *(const short8*)(Wb + (ob + l15) * 128 + kk * 32 + l4 * 8);
  }
  floatx4 ag[8], ab[8];
#pragma unroll
  for (int ni = 0; ni < 8; ++ni) {
    ag[ni] = (floatx4){0.f, 0.f, 0.f, 0.f};
    ab[ni] = (floatx4){0.f, 0.f, 0.f, 0.f};
  }
#pragma unroll
  for (int kk = 0; kk < 4; ++kk) {
    int seg = kk * 4 + l4;
#pragma unroll
    for (int ni = 0; ni < 8; ++ni) {
      short8 tf = *(const short8*)(&T2[(ni * 16 + l15) * 128 + ((seg ^ l15) << 3)]);
      ag[ni] = __builtin_amdgcn_mfma_f32_16x16x32_bf16(wgf[kk], tf, ag[ni], 0, 0, 0);
      ab[ni] = __builtin_amdgcn_mfma_f32_16x16x32_bf16(wbf2[kk], tf, ab[ni], 0, 0, 0);
    }
  }
  __syncthreads();   // T2 fully consumed

  // ---- Epilogue in two o-halves of 64 (MB = 32 KB) ----
#pragma unroll
  for (int h = 0; h < 2; ++h) {
    if ((wave >> 2) == h) {
      int orel0 = (wave & 3) * 16;
#pragma unroll
      for (int ni = 0; ni < 8; ++ni) {
        int tok = ni * 16 + l15;
#pragma unroll
        for (int j = 0; j < 4; ++j) {
          int orel = orel0 + l4 * 4 + j;
          int o = h * 64 + orel;
          float g = ag[ni][j] + gpb[o];
          float t1 = __expf(2.f * g);
          float m = 2.f - 2.f / (t1 + 1.f);          // 1 + tanh(g), inf-safe
          float bt = ab[ni][j] + bpb[o];
          int rot = ((orel & 3) << 2) | ((orel >> 2) & 3);
          MB[orel * 128 + ((((tok >> 3) ^ rot) << 3) | (tok & 7))] =
              (u32)f2bf(m) | ((u32)f2bf(bt) << 16);
        }
      }
    }
    __syncthreads();
#pragma unroll
    for (int it = 0; it < 2; ++it) {
      int idx = it * 512 + tid;
      int orel = idx >> 4, seg = idx & 15;
      int o = h * 64 + orel;
      int rot = ((orel & 3) << 2) | ((orel >> 2) & 3);
      int sp = ((seg ^ rot) << 3);
      uint4 mb0 = *(const uint4*)(&MB[orel * 128 + sp]);
      uint4 mb1 = *(const uint4*)(&MB[orel * 128 + sp + 4]);
      float* op = outp + ((size_t)(b * 128 + o)) * 16384 + chunk * 128 + seg * 8;
      float4 o0 = *(float4*)op;
      float4 o1 = *(float4*)(op + 4);
      o0.x = o0.x * bf2f((u16)(mb0.x & 0xffff)) + bf2f((u16)(mb0.x >> 16));
      o0.y = o0.y * bf2f((u16)(mb0.y & 0xffff)) + bf2f((u16)(mb0.y >> 16));
      o0.z = o0.z * bf2f((u16)(mb0.z & 0xffff)) + bf2f((u16)(mb0.z >> 16));
      o0.w = o0.w * bf2f((u16)(mb0.w & 0xffff)) + bf2f((u16)(mb0.w >> 16));
      o1.x = o1.x * bf2f((u16)(mb1.x & 0xffff)) + bf2f((u16)(mb1.x >> 16));
      o1.y = o1.y * bf2f((u16)(mb1.y & 0xffff)) + bf2f((u16)(mb1.y >> 16));
      o1.z = o1.z * bf2f((u16)(mb1.z & 0xffff)) + bf2f((u16)(mb1.z >> 16));
      o1.w = o1.w * bf2f((u16)(mb1.w & 0xffff)) + bf2f((u16)(mb1.w >> 16));
      *(float4*)op = o0;
      *(float4*)(op + 4) = o1;
    }
    __syncthreads();
  }
}

// ---------------------------------------------------------------------------
extern "C" void kernel_launch(void* const* d_in, const int* in_sizes, int n_in,
                              void* d_out, int out_size, void* d_ws, size_t ws_size,
                              hipStream_t stream) {
  const float* x        = (const float*)d_in[0];
  const float* gs       = (const float*)d_in[1];
  const float* cond_gw  = (const float*)d_in[2];
  const float* cond_gb  = (const float*)d_in[3];
  const float* cond_bw  = (const float*)d_in[4];
  const float* cond_bb  = (const float*)d_in[5];
  const float* td       = (const float*)d_in[6];
  const float* Wk       = (const float*)d_in[7];
  const float* Wv       = (const float*)d_in[8];
  const float* Wr       = (const float*)d_in[9];
  const float* Wo       = (const float*)d_in[10];
  const float* ln_g     = (const float*)d_in[11];
  const float* ln_b     = (const float*)d_in[12];
  const float* gp_w     = (const float*)d_in[13];
  const float* gp_b     = (const float*)d_in[14];
  const float* bp_w     = (const float*)d_in[15];
  const float* bp_b     = (const float*)d_in[16];
  float* outp = (float*)d_out;

  char* w = (char*)d_ws;
  float* gamma = (float*)w; w += 4096;
  float* beta  = (float*)w; w += 4096;
  u16* wbf     = (u16*)w;   w += 6 * 2 * 16384 * sizeof(u16);     // 384 KB
  u16* xn      = (u16*)w;   w += (size_t)MM * 128 * sizeof(u16);  // 32 MB
  u16* ybuf    = (u16*)w;   w += (size_t)MM * 128 * sizeof(u16);  // 32 MB
  float* Sbuf  = (float*)w; w += (size_t)NCH * 1024 * sizeof(float);  // 1 MB
  float* ibuf  = (float*)w; w += (size_t)NCH * 1024 * sizeof(float);  // 1 MB

  film_kernel<<<4, 256, 0, stream>>>(gs, cond_gw, cond_gb, cond_bw, cond_bb, gamma, beta);
  convert_kernel<<<768, 256, 0, stream>>>(Wk, Wv, Wr, Wo, gp_w, bp_w, wbf);

  for (int blk = 0; blk < 2; ++blk) {
    const u16* bWk = wbf + 0 * 32768 + blk * 16384;
    const u16* bWv = wbf + 1 * 32768 + blk * 16384;
    const u16* bWr = wbf + 2 * 32768 + blk * 16384;
    const u16* bWo = wbf + 3 * 32768 + blk * 16384;
    const u16* bGp = wbf + 4 * 32768 + blk * 16384;
    const u16* bBp = wbf + 5 * 32768 + blk * 16384;
    const float* tdi = td + blk * 128;

    if (blk == 0)
      prep_kernel<1><<<2048, 256, 0, stream>>>(x, gamma, beta, ln_g, ln_b, outp, xn);
    else
      prep_kernel<0><<<2048, 256, 0, stream>>>(outp, nullptr, nullptr, ln_g + 128,
                                               ln_b + 128, nullptr, xn);

    gemm_S_kernel<<<1024, 256, 0, stream>>>(xn, bWk, tdi, Sbuf);
    scan2_kernel<<<256, 256, 0, stream>>>(Sbuf, tdi, ibuf);
    gemm_y_kernel<<<2048, 256, 0, stream>>>(xn, bWv, bWr, bWk, tdi, ibuf, ybuf);
    tail_kernel<<<1024, 512, 0, stream>>>(ybuf, bWo, bGp, bBp,
                                          gp_b + blk * 128, bp_b + blk * 128, outp);
  }
}

// Round 11
// 267.600 us; speedup vs baseline: 1.1979x; 1.1570x over previous
//
#include <hip/hip_runtime.h>
#include <hip/hip_bf16.h>

// Problem constants
#define BB 8
#define CC 128
#define NN 16384            // 128*128 tokens per batch
#define MM (BB * NN)        // 131072
#define NCH 256             // scan chunks per batch-row (64 tokens each)
#define CLN 64              // chunk length

typedef __attribute__((ext_vector_type(8))) short short8;   // 8 x bf16 (4 VGPRs)
typedef __attribute__((ext_vector_type(4))) float floatx4;  // MFMA accumulator
typedef unsigned short u16;
typedef unsigned int u32;

__device__ __forceinline__ float bf2f(u16 h) {
  u32 u = ((u32)h) << 16;
  return __builtin_bit_cast(float, u);
}
__device__ __forceinline__ u16 f2bf(float f) {
  u32 u = __builtin_bit_cast(u32, f);
  u32 r = u + 0x7FFFu + ((u >> 16) & 1u);   // round-to-nearest-even
  return (u16)(r >> 16);
}

// ---------------------------------------------------------------------------
// FiLM params: gamma[b,c] = gs[b,:]·cond_gw[c,:] + cond_gb[c]; beta likewise.
__global__ void film_kernel(const float* __restrict__ gs, const float* __restrict__ gw,
                            const float* __restrict__ gb, const float* __restrict__ bw,
                            const float* __restrict__ bb, float* __restrict__ gamma,
                            float* __restrict__ beta) {
  int idx = blockIdx.x * 256 + threadIdx.x;   // 0..1023
  int b = idx >> 7, c = idx & 127;
  float sg = 0.f, sb = 0.f;
  for (int j = 0; j < 128; ++j) {
    float g = gs[b * 128 + j];
    sg += g * gw[c * 128 + j];
    sb += g * bw[c * 128 + j];
  }
  gamma[idx] = sg + gb[c];
  beta[idx] = sb + bb[c];
}

// ---------------------------------------------------------------------------
// Convert all 6 weight tensors (each (2,128,128) f32) to bf16, packed
// [which][block][o][c] at dst + which*32768.
__global__ void convert_kernel(const float* __restrict__ Wk, const float* __restrict__ Wv,
                               const float* __restrict__ Wr, const float* __restrict__ Wo,
                               const float* __restrict__ gp, const float* __restrict__ bp,
                               u16* __restrict__ dst) {
  int idx = blockIdx.x * 256 + threadIdx.x;   // 0..196607
  int which = idx >> 15;
  int off = idx & 32767;
  const float* s;
  switch (which) {
    case 0: s = Wk; break; case 1: s = Wv; break; case 2: s = Wr; break;
    case 3: s = Wo; break; case 4: s = gp; break; default: s = bp; break;
  }
  dst[idx] = f2bf(s[off]);
}

// ---------------------------------------------------------------------------
// Prep: (UPS=1) bilinear 2x upsample + write x_up to out(BCHW) + FiLM + LN -> xn bf16
//       (UPS=0) read out(BCHW) + LN -> xn bf16
template <int UPS>
__global__ __launch_bounds__(256) void prep_kernel(
    const float* __restrict__ src, const float* __restrict__ gamma,
    const float* __restrict__ beta, const float* __restrict__ lng,
    const float* __restrict__ lnb, float* __restrict__ outp, u16* __restrict__ xn) {
  __shared__ float tile[64][129];
  __shared__ float smu[64], srs[64];
  int bidx = blockIdx.x;              // 0..2047
  int half = bidx & 1;
  int ho = (bidx >> 1) & 127;
  int b = bidx >> 8;
  int wo0 = half * 64;
  int tid = threadIdx.x;
  int tk = tid & 63;
  int wo = wo0 + tk;
  int c0 = tid >> 6;                  // 0..3
  int j0 = 0, j1 = 0, i0 = 0, i1 = 0;
  float wy0 = 0.f, wy1 = 0.f, wx0 = 0.f, wx1 = 0.f;
  if (UPS) {
    int jj = ho >> 1;
    if ((ho & 1) == 0) { j0 = jj > 0 ? jj - 1 : 0; j1 = jj; wy0 = 0.25f; wy1 = 0.75f; }
    else               { j0 = jj; j1 = jj < 63 ? jj + 1 : 63; wy0 = 0.75f; wy1 = 0.25f; }
    int ii = wo >> 1;
    if ((wo & 1) == 0) { i0 = ii > 0 ? ii - 1 : 0; i1 = ii; wx0 = 0.25f; wx1 = 0.75f; }
    else               { i0 = ii; i1 = ii < 63 ? ii + 1 : 63; wx0 = 0.75f; wx1 = 0.25f; }
  }
  for (int it = 0; it < 32; ++it) {
    int c = it * 4 + c0;
    float v;
    if (UPS) {
      const float* xp = src + ((size_t)(b * 128 + c)) * 4096;
      v = wy0 * (wx0 * xp[j0 * 64 + i0] + wx1 * xp[j0 * 64 + i1]) +
          wy1 * (wx0 * xp[j1 * 64 + i0] + wx1 * xp[j1 * 64 + i1]);
      outp[((size_t)(b * 128 + c)) * 16384 + ho * 128 + wo] = v;
      v = v * (1.f + gamma[b * 128 + c]) + beta[b * 128 + c];
    } else {
      v = src[((size_t)(b * 128 + c)) * 16384 + ho * 128 + wo];
    }
    tile[tk][c] = v;
  }
  __syncthreads();
  {
    int token = tid >> 2, q = tid & 3;
    float s = 0.f, s2 = 0.f;
    for (int j = 0; j < 32; ++j) { float v = tile[token][q * 32 + j]; s += v; s2 += v * v; }
    s += __shfl_xor(s, 1); s2 += __shfl_xor(s2, 1);
    s += __shfl_xor(s, 2); s2 += __shfl_xor(s2, 2);
    if (q == 0) {
      float mu = s * 0.0078125f;
      float var = s2 * 0.0078125f - mu * mu;
      smu[token] = mu;
      srs[token] = rsqrtf(var + 1e-5f);
    }
  }
  __syncthreads();
  size_t base = ((size_t)b * 16384 + ho * 128 + wo0) * 128;
  for (int it = 0; it < 32; ++it) {
    int idx = it * 256 + tid;
    int token = idx >> 7, c = idx & 127;
    float v = (tile[token][c] - smu[token]) * srs[token] * lng[c] + lnb[c];
    xn[base + idx] = f2bf(v);
  }
}

// ---------------------------------------------------------------------------
// gemm_S: k-GEMM (staged weights), fused decay-weighted sums for TWO 64-token
// halves -> Sbuf (chunk granularity = 64 tokens).
__global__ __launch_bounds__(256) void gemm_S_kernel(
    const u16* __restrict__ A, const u16* __restrict__ W0,
    const float* __restrict__ td, float* __restrict__ Sbuf) {
  __shared__ u16 Alds[128 * 128];
  __shared__ u16 Wlds[128 * 128];
  __shared__ float Sred[512];         // [wave][c]
  int tid = threadIdx.x;
  int wave = tid >> 6, lane = tid & 63;
  int l15 = lane & 15, l4 = lane >> 4;
  size_t row0 = (size_t)blockIdx.x * 128;
#pragma unroll
  for (int it = 0; it < 8; ++it) {
    int idx = it * 256 + tid;
    int rr = idx >> 4, s = idx & 15;
    uint4 d = *(const uint4*)(A + (row0 + rr) * 128 + s * 8);
    *(uint4*)(&Alds[rr * 128 + ((s ^ (rr & 15)) << 3)]) = d;
  }
#pragma unroll
  for (int it = 0; it < 8; ++it) {
    int idx = it * 256 + tid;
    int rr = idx >> 4, s = idx & 15;
    uint4 d = *(const uint4*)(W0 + rr * 128 + s * 8);
    *(uint4*)(&Wlds[rr * 128 + ((s ^ (rr & 15)) << 3)]) = d;
  }
  __syncthreads();
  floatx4 acc[2][8];
#pragma unroll
  for (int mi = 0; mi < 2; ++mi)
#pragma unroll
    for (int ni = 0; ni < 8; ++ni) acc[mi][ni] = (floatx4){0.f, 0.f, 0.f, 0.f};
#pragma unroll
  for (int kk = 0; kk < 4; ++kk) {
    int seg = kk * 4 + l4;
    short8 a0 = *(const short8*)(&Alds[(wave * 32 + l15) * 128 + ((seg ^ l15) << 3)]);
    short8 a1 = *(const short8*)(&Alds[(wave * 32 + 16 + l15) * 128 + ((seg ^ l15) << 3)]);
#pragma unroll
    for (int ni = 0; ni < 8; ++ni) {
      short8 bfr = *(const short8*)(&Wlds[(ni * 16 + l15) * 128 + ((seg ^ l15) << 3)]);
      acc[0][ni] = __builtin_amdgcn_mfma_f32_16x16x32_bf16(a0, bfr, acc[0][ni], 0, 0, 0);
      acc[1][ni] = __builtin_amdgcn_mfma_f32_16x16x32_bf16(a1, bfr, acc[1][ni], 0, 0, 0);
    }
  }
  // Half-local S: token t_loc = (wave&1)*32 + mi*16 + l4*4 + j; weight d^{63-t_loc}
  int T0h = (wave & 1) * 32 + l4 * 4;
#pragma unroll
  for (int ni = 0; ni < 8; ++ni) {
    int c = ni * 16 + l15;
    float a = fmaxf(td[c], 0.f);
    float E = __expf(-a * (float)(63 - T0h));   // d^{63-T0h}
    float r1 = __expf(a);                        // d^{-1}
    float r16 = __expf(a * 16.f);
    float w = E, sum;
    sum  = w * acc[0][ni][0]; w *= r1;
    sum += w * acc[0][ni][1]; w *= r1;
    sum += w * acc[0][ni][2]; w *= r1;
    sum += w * acc[0][ni][3];
    w = E * r16;
    sum += w * acc[1][ni][0]; w *= r1;
    sum += w * acc[1][ni][1]; w *= r1;
    sum += w * acc[1][ni][2]; w *= r1;
    sum += w * acc[1][ni][3];
    sum += __shfl_xor(sum, 16);
    sum += __shfl_xor(sum, 32);
    if (l4 == 0) Sred[wave * 128 + c] = sum;
  }
  __syncthreads();
  if (tid < 128) {
    int hc0 = (blockIdx.x & 127) * 2;
    int bo = (blockIdx.x >> 7) * 128 + tid;
    Sbuf[(size_t)hc0 * 1024 + bo]       = Sred[tid] + Sred[128 + tid];
    Sbuf[(size_t)(hc0 + 1) * 1024 + bo] = Sred[256 + tid] + Sred[384 + tid];
  }
}

// ---------------------------------------------------------------------------
// Scan phase 2: per (b,c) scan over 256 chunks of 64 tokens; one wave, 4/lane.
__global__ __launch_bounds__(256) void scan2_kernel(const float* __restrict__ S,
                                                    const float* __restrict__ td,
                                                    float* __restrict__ init) {
  int wave = threadIdx.x >> 6, lane = threadIdx.x & 63;
  int bc = blockIdx.x * 4 + wave;   // 0..1023
  int c = bc & 127;
  float a1 = __expf(-fmaxf(td[c], 0.f) * 64.f);   // decay^CLN
  float s0 = S[(size_t)(4 * lane + 0) * 1024 + bc];
  float s1 = S[(size_t)(4 * lane + 1) * 1024 + bc];
  float s2 = S[(size_t)(4 * lane + 2) * 1024 + bc];
  float s3 = S[(size_t)(4 * lane + 3) * 1024 + bc];
  float a2 = a1 * a1;
  float T = s3 + a1 * s2 + a2 * (s1 + a1 * s0);   // 4-seg combined
  float s = T, a = a2 * a2;                        // carry d^256
  for (int off = 1; off < 64; off <<= 1) {
    float ss = __shfl_up(s, off);
    float aa = __shfl_up(a, off);
    if (lane >= off) { s = s + a * ss; a = a * aa; }
  }
  float e = __shfl_up(s, 1);          // exclusive over 4-groups
  if (lane == 0) e = 0.f;
  init[(size_t)(4 * lane + 0) * 1024 + bc] = e;
  float e1 = a1 * e + s0;  init[(size_t)(4 * lane + 1) * 1024 + bc] = e1;
  float e2 = a1 * e1 + s1; init[(size_t)(4 * lane + 2) * 1024 + bc] = e2;
  float e3 = a1 * e2 + s2; init[(size_t)(4 * lane + 3) * 1024 + bc] = e3;
}

// ---------------------------------------------------------------------------
// gemm_y v3: M=64 tokens/block, each wave owns a 32-channel N-slice (weights in
// registers, tail-style). k GEMM -> in-wave scan (seeded with init) -> r GEMM
// (sigmoid, packed) -> v GEMM -> y. 17 KB LDS. UNCAPPED registers (R10's
// __launch_bounds__(256,4) forced a 64-VGPR allocation -> ~145 MB spill traffic).
__global__ __launch_bounds__(256) void gemm_y_kernel(
    const u16* __restrict__ xn, const u16* __restrict__ Wv_,
    const u16* __restrict__ Wr_, const u16* __restrict__ Wk_,
    const float* __restrict__ td, const float* __restrict__ init_,
    u16* __restrict__ outY) {
  __shared__ u16 Alds[64 * 128];      // 16 KB: xn half-tile -> later YW
  __shared__ float ILS[128];
  int tid = threadIdx.x;
  int wave = tid >> 6, lane = tid & 63;
  int l15 = lane & 15, l4 = lane >> 4;
  size_t row0 = (size_t)blockIdx.x * 64;
  int bI = blockIdx.x >> 8, hcI = blockIdx.x & 255;
  if (tid < 128) ILS[tid] = init_[(size_t)hcI * 1024 + bI * 128 + tid];
#pragma unroll
  for (int it = 0; it < 4; ++it) {
    int idx = it * 256 + tid;
    int rr = idx >> 4, s = idx & 15;
    uint4 d = *(const uint4*)(xn + (row0 + rr) * 128 + s * 8);
    *(uint4*)(&Alds[rr * 128 + ((s ^ (rr & 15)) << 3)]) = d;
  }
  int ob = wave * 32;
  float dd[2], d4a[2];
#pragma unroll
  for (int ni = 0; ni < 2; ++ni) {
    float a = fmaxf(td[ob + ni * 16 + l15], 0.f);
    float d = __expf(-a);
    dd[ni] = d;
    d4a[ni] = d * d * d * d;
  }
  __syncthreads();

  // ---- k GEMM (per-wave weight slice in regs) ----
  floatx4 acc[4][2];
#pragma unroll
  for (int mi = 0; mi < 4; ++mi)
#pragma unroll
    for (int ni = 0; ni < 2; ++ni) acc[mi][ni] = (floatx4){0.f, 0.f, 0.f, 0.f};
#pragma unroll
  for (int kk = 0; kk < 4; ++kk) {
    short8 w0 = *(const short8*)(Wk_ + (ob + l15) * 128 + kk * 32 + l4 * 8);
    short8 w1 = *(const short8*)(Wk_ + (ob + 16 + l15) * 128 + kk * 32 + l4 * 8);
#pragma unroll
    for (int mi = 0; mi < 4; ++mi) {
      short8 af = *(const short8*)(&Alds[(mi * 16 + l15) * 128 + (((kk * 4 + l4) ^ l15) << 3)]);
      acc[mi][0] = __builtin_amdgcn_mfma_f32_16x16x32_bf16(af, w0, acc[mi][0], 0, 0, 0);
      acc[mi][1] = __builtin_amdgcn_mfma_f32_16x16x32_bf16(af, w1, acc[mi][1], 0, 0, 0);
    }
  }

  // ---- in-wave weighted prefix scan (token = mi*16 + l4*4 + j) ----
  u32 sp[4][2][2];                    // s packed bf16
  {
    float Elr[4][2], Bm[4][2];
#pragma unroll
    for (int ni = 0; ni < 2; ++ni) {
      float d = dd[ni], d4 = d4a[ni];
      float d8 = d4 * d4;
#pragma unroll
      for (int mi = 0; mi < 4; ++mi) {
        float p0 = acc[mi][ni][0];
        float p1 = d * p0 + acc[mi][ni][1];
        float p2 = d * p1 + acc[mi][ni][2];
        float p3 = d * p2 + acc[mi][ni][3];
        acc[mi][ni][0] = p0; acc[mi][ni][1] = p1;
        acc[mi][ni][2] = p2; acc[mi][ni][3] = p3;
        float Iv = p3;
        float t1 = __shfl_up(Iv, 16);
        if (l4 >= 1) Iv += d4 * t1;
        float t2 = __shfl_up(Iv, 32);
        if (l4 >= 2) Iv += d8 * t2;
        float ex = __shfl_up(Iv, 16);
        Elr[mi][ni] = (l4 == 0) ? 0.f : ex;
        Bm[mi][ni] = __shfl(Iv, 48 + l15);
      }
    }
#pragma unroll
    for (int ni = 0; ni < 2; ++ni) {
      float d = dd[ni], d4 = d4a[ni];
      float d8 = d4 * d4, d12 = d8 * d4, d16 = d8 * d8;
      float d4l = (l4 == 0) ? 1.f : ((l4 == 1) ? d4 : ((l4 == 2) ? d8 : d12));
      float e = ILS[ob + ni * 16 + l15];
#pragma unroll
      for (int mi = 0; mi < 4; ++mi) {
        float Sb = Elr[mi][ni] + d4l * e;
        float w = d;
        float s0 = acc[mi][ni][0] + w * Sb; w *= d;
        float s1 = acc[mi][ni][1] + w * Sb; w *= d;
        float s2 = acc[mi][ni][2] + w * Sb; w *= d;
        float s3 = acc[mi][ni][3] + w * Sb;
        sp[mi][ni][0] = (u32)f2bf(s0) | ((u32)f2bf(s1) << 16);
        sp[mi][ni][1] = (u32)f2bf(s2) | ((u32)f2bf(s3) << 16);
        e = e * d16 + Bm[mi][ni];
      }
    }
  }

  // ---- r GEMM -> sigmoid packed ----
  u32 rp[4][2][2];
  {
#pragma unroll
    for (int mi = 0; mi < 4; ++mi)
#pragma unroll
      for (int ni = 0; ni < 2; ++ni) acc[mi][ni] = (floatx4){0.f, 0.f, 0.f, 0.f};
#pragma unroll
    for (int kk = 0; kk < 4; ++kk) {
      short8 w0 = *(const short8*)(Wr_ + (ob + l15) * 128 + kk * 32 + l4 * 8);
      short8 w1 = *(const short8*)(Wr_ + (ob + 16 + l15) * 128 + kk * 32 + l4 * 8);
#pragma unroll
      for (int mi = 0; mi < 4; ++mi) {
        short8 af = *(const short8*)(&Alds[(mi * 16 + l15) * 128 + (((kk * 4 + l4) ^ l15) << 3)]);
        acc[mi][0] = __builtin_amdgcn_mfma_f32_16x16x32_bf16(af, w0, acc[mi][0], 0, 0, 0);
        acc[mi][1] = __builtin_amdgcn_mfma_f32_16x16x32_bf16(af, w1, acc[mi][1], 0, 0, 0);
      }
    }
#pragma unroll
    for (int mi = 0; mi < 4; ++mi)
#pragma unroll
      for (int ni = 0; ni < 2; ++ni) {
        float r0 = 1.f / (1.f + __expf(-acc[mi][ni][0]));
        float r1 = 1.f / (1.f + __expf(-acc[mi][ni][1]));
        float r2 = 1.f / (1.f + __expf(-acc[mi][ni][2]));
        float r3 = 1.f / (1.f + __expf(-acc[mi][ni][3]));
        rp[mi][ni][0] = (u32)f2bf(r0) | ((u32)f2bf(r1) << 16);
        rp[mi][ni][1] = (u32)f2bf(r2) | ((u32)f2bf(r3) << 16);
      }
  }

  // ---- v GEMM ----
#pragma unroll
  for (int mi = 0; mi < 4; ++mi)
#pragma unroll
    for (int ni = 0; ni < 2; ++ni) acc[mi][ni] = (floatx4){0.f, 0.f, 0.f, 0.f};
#pragma unroll
  for (int kk = 0; kk < 4; ++kk) {
    short8 w0 = *(const short8*)(Wv_ + (ob + l15) * 128 + kk * 32 + l4 * 8);
    short8 w1 = *(const short8*)(Wv_ + (ob + 16 + l15) * 128 + kk * 32 + l4 * 8);
#pragma unroll
    for (int mi = 0; mi < 4; ++mi) {
      short8 af = *(const short8*)(&Alds[(mi * 16 + l15) * 128 + (((kk * 4 + l4) ^ l15) << 3)]);
      acc[mi][0] = __builtin_amdgcn_mfma_f32_16x16x32_bf16(af, w0, acc[mi][0], 0, 0, 0);
      acc[mi][1] = __builtin_amdgcn_mfma_f32_16x16x32_bf16(af, w1, acc[mi][1], 0, 0, 0);
    }
  }
  __syncthreads();   // all Alds reads done before YW overwrite

  // ---- y = sig(r)*(s + v) -> YW (= Alds region), then coalesced store ----
  u16* YW = Alds;
#pragma unroll
  for (int mi = 0; mi < 4; ++mi)
#pragma unroll
    for (int ni = 0; ni < 2; ++ni) {
      int c = ob + ni * 16 + l15;
#pragma unroll
      for (int j = 0; j < 4; ++j) {
        float s = bf2f((u16)(sp[mi][ni][j >> 1] >> ((j & 1) * 16)));
        float rs = bf2f((u16)(rp[mi][ni][j >> 1] >> ((j & 1) * 16)));
        float y = rs * (s + acc[mi][ni][j]);
        int row = mi * 16 + l4 * 4 + j;
        int colsw = c ^ (((row >> 2) & 3) << 4);
        YW[row * 128 + colsw] = f2bf(y);
      }
    }
  __syncthreads();
#pragma unroll
  for (int it = 0; it < 4; ++it) {
    int idx = it * 256 + tid;
    int row = idx >> 4, cb = (idx & 15) * 8;
    int csw = cb ^ (((row >> 2) & 3) << 4);
    uint4 dv = *(const uint4*)(&YW[row * 128 + csw]);
    *(uint4*)(outY + (row0 + row) * 128 + cb) = dv;
  }
}

// ---------------------------------------------------------------------------
// Tail v5: Y staged (pure swizzled copy) -> t = Wo·y^T -> T2 -> g/bt GEMMs ->
// out = out*(1+tanh(g)) + bt. 32 KB LDS, 512 thr.
__global__ __launch_bounds__(512, 4) void tail_kernel(
    const u16* __restrict__ yl,
    const u16* __restrict__ Wo, const u16* __restrict__ Wg, const u16* __restrict__ Wb,
    const float* __restrict__ gpb, const float* __restrict__ bpb,
    float* __restrict__ outp) {
  __shared__ u32 SMEM[8192];          // 32 KB: Y -> T2 -> MB
  u16* Y = (u16*)SMEM;
  u16* T2 = (u16*)SMEM;
  u32* MB = SMEM;

  int tid = threadIdx.x;
  int wave = tid >> 6, lane = tid & 63;
  int l15 = lane & 15, l4 = lane >> 4;
  int b = blockIdx.x >> 7;
  int chunk = blockIdx.x & 127;
  size_t ebase = ((size_t)b * 16384 + (size_t)chunk * 128) * 128;

  // ---- Y stage: swizzled copy ----
#pragma unroll
  for (int it = 0; it < 4; ++it) {
    int idx = it * 512 + tid;         // 0..2047
    int t = idx >> 4;
    int c8 = (idx & 15) * 8;
    uint4 yv = *(const uint4*)(yl + ebase + (size_t)t * 128 + c8);
    *(uint4*)(&Y[t * 128 + (((c8 >> 3) ^ (t & 15)) << 3)]) = yv;
  }
  __syncthreads();

  // ---- GEMM1: t[o][tok] = Wo(16 rows/wave) · Y^T ----
  int ob = wave * 16;
  short8 wof[4];
#pragma unroll
  for (int kk = 0; kk < 4; ++kk)
    wof[kk] = *(const short8*)(Wo + (ob + l15) * 128 + kk * 32 + l4 * 8);
  floatx4 acc[8];
#pragma unroll
  for (int ni = 0; ni < 8; ++ni) acc[ni] = (floatx4){0.f, 0.f, 0.f, 0.f};
#pragma unroll
  for (int kk = 0; kk < 4; ++kk) {
    int seg = kk * 4 + l4;
#pragma unroll
    for (int ni = 0; ni < 8; ++ni) {
      short8 yf = *(const short8*)(&Y[(ni * 16 + l15) * 128 + ((seg ^ l15) << 3)]);
      acc[ni] = __builtin_amdgcn_mfma_f32_16x16x32_bf16(wof[kk], yf, acc[ni], 0, 0, 0);
    }
  }
  __syncthreads();   // all Y reads complete before overwrite

  // write T2 [tok][o] bf16, swizzled, packed o-pairs
#pragma unroll
  for (int ni = 0; ni < 8; ++ni) {
    int tok = ni * 16 + l15;
#pragma unroll
    for (int j = 0; j < 4; j += 2) {
      int o = ob + l4 * 4 + j;
      u32 pack = (u32)f2bf(acc[ni][j]) | ((u32)f2bf(acc[ni][j + 1]) << 16);
      int pos = tok * 128 + ((((o >> 3) ^ (tok & 15)) << 3) | (o & 7));
      *(u32*)(T2 + pos) = pack;
    }
  }
  __syncthreads();

  // ---- GEMM2: g/bt [o'][tok] over K=o ----
  short8 wgf[4], wbf2[4];
#pragma unroll
  for (int kk = 0; kk < 4; ++kk) {
    wgf[kk]  = *(const short8*)(Wg + (ob + l15) * 128 + kk * 32 + l4 * 8);
    wbf2[kk] = *(const short8*)(Wb + (ob + l15) * 128 + kk * 32 + l4 * 8);
  }
  floatx4 ag[8], ab[8];
#pragma unroll
  for (int ni = 0; ni < 8; ++ni) {
    ag[ni] = (floatx4){0.f, 0.f, 0.f, 0.f};
    ab[ni] = (floatx4){0.f, 0.f, 0.f, 0.f};
  }
#pragma unroll
  for (int kk = 0; kk < 4; ++kk) {
    int seg = kk * 4 + l4;
#pragma unroll
    for (int ni = 0; ni < 8; ++ni) {
      short8 tf = *(const short8*)(&T2[(ni * 16 + l15) * 128 + ((seg ^ l15) << 3)]);
      ag[ni] = __builtin_amdgcn_mfma_f32_16x16x32_bf16(wgf[kk], tf, ag[ni], 0, 0, 0);
      ab[ni] = __builtin_amdgcn_mfma_f32_16x16x32_bf16(wbf2[kk], tf, ab[ni], 0, 0, 0);
    }
  }
  __syncthreads();   // T2 fully consumed

  // ---- Epilogue in two o-halves of 64 (MB = 32 KB) ----
#pragma unroll
  for (int h = 0; h < 2; ++h) {
    if ((wave >> 2) == h) {
      int orel0 = (wave & 3) * 16;
#pragma unroll
      for (int ni = 0; ni < 8; ++ni) {
        int tok = ni * 16 + l15;
#pragma unroll
        for (int j = 0; j < 4; ++j) {
          int orel = orel0 + l4 * 4 + j;
          int o = h * 64 + orel;
          float g = ag[ni][j] + gpb[o];
          float t1 = __expf(2.f * g);
          float m = 2.f - 2.f / (t1 + 1.f);          // 1 + tanh(g), inf-safe
          float bt = ab[ni][j] + bpb[o];
          int rot = ((orel & 3) << 2) | ((orel >> 2) & 3);
          MB[orel * 128 + ((((tok >> 3) ^ rot) << 3) | (tok & 7))] =
              (u32)f2bf(m) | ((u32)f2bf(bt) << 16);
        }
      }
    }
    __syncthreads();
#pragma unroll
    for (int it = 0; it < 2; ++it) {
      int idx = it * 512 + tid;
      int orel = idx >> 4, seg = idx & 15;
      int o = h * 64 + orel;
      int rot = ((orel & 3) << 2) | ((orel >> 2) & 3);
      int sp = ((seg ^ rot) << 3);
      uint4 mb0 = *(const uint4*)(&MB[orel * 128 + sp]);
      uint4 mb1 = *(const uint4*)(&MB[orel * 128 + sp + 4]);
      float* op = outp + ((size_t)(b * 128 + o)) * 16384 + chunk * 128 + seg * 8;
      float4 o0 = *(float4*)op;
      float4 o1 = *(float4*)(op + 4);
      o0.x = o0.x * bf2f((u16)(mb0.x & 0xffff)) + bf2f((u16)(mb0.x >> 16));
      o0.y = o0.y * bf2f((u16)(mb0.y & 0xffff)) + bf2f((u16)(mb0.y >> 16));
      o0.z = o0.z * bf2f((u16)(mb0.z & 0xffff)) + bf2f((u16)(mb0.z >> 16));
      o0.w = o0.w * bf2f((u16)(mb0.w & 0xffff)) + bf2f((u16)(mb0.w >> 16));
      o1.x = o1.x * bf2f((u16)(mb1.x & 0xffff)) + bf2f((u16)(mb1.x >> 16));
      o1.y = o1.y * bf2f((u16)(mb1.y & 0xffff)) + bf2f((u16)(mb1.y >> 16));
      o1.z = o1.z * bf2f((u16)(mb1.z & 0xffff)) + bf2f((u16)(mb1.z >> 16));
      o1.w = o1.w * bf2f((u16)(mb1.w & 0xffff)) + bf2f((u16)(mb1.w >> 16));
      *(float4*)op = o0;
      *(float4*)(op + 4) = o1;
    }
    __syncthreads();
  }
}

// ---------------------------------------------------------------------------
extern "C" void kernel_launch(void* const* d_in, const int* in_sizes, int n_in,
                              void* d_out, int out_size, void* d_ws, size_t ws_size,
                              hipStream_t stream) {
  const float* x        = (const float*)d_in[0];
  const float* gs       = (const float*)d_in[1];
  const float* cond_gw  = (const float*)d_in[2];
  const float* cond_gb  = (const float*)d_in[3];
  const float* cond_bw  = (const float*)d_in[4];
  const float* cond_bb  = (const float*)d_in[5];
  const float* td       = (const float*)d_in[6];
  const float* Wk       = (const float*)d_in[7];
  const float* Wv       = (const float*)d_in[8];
  const float* Wr       = (const float*)d_in[9];
  const float* Wo       = (const float*)d_in[10];
  const float* ln_g     = (const float*)d_in[11];
  const float* ln_b     = (const float*)d_in[12];
  const float* gp_w     = (const float*)d_in[13];
  const float* gp_b     = (const float*)d_in[14];
  const float* bp_w     = (const float*)d_in[15];
  const float* bp_b     = (const float*)d_in[16];
  float* outp = (float*)d_out;

  char* w = (char*)d_ws;
  float* gamma = (float*)w; w += 4096;
  float* beta  = (float*)w; w += 4096;
  u16* wbf     = (u16*)w;   w += 6 * 2 * 16384 * sizeof(u16);     // 384 KB
  u16* xn      = (u16*)w;   w += (size_t)MM * 128 * sizeof(u16);  // 32 MB
  u16* ybuf    = (u16*)w;   w += (size_t)MM * 128 * sizeof(u16);  // 32 MB
  float* Sbuf  = (float*)w; w += (size_t)NCH * 1024 * sizeof(float);  // 1 MB
  float* ibuf  = (float*)w; w += (size_t)NCH * 1024 * sizeof(float);  // 1 MB

  film_kernel<<<4, 256, 0, stream>>>(gs, cond_gw, cond_gb, cond_bw, cond_bb, gamma, beta);
  convert_kernel<<<768, 256, 0, stream>>>(Wk, Wv, Wr, Wo, gp_w, bp_w, wbf);

  for (int blk = 0; blk < 2; ++blk) {
    const u16* bWk = wbf + 0 * 32768 + blk * 16384;
    const u16* bWv = wbf + 1 * 32768 + blk * 16384;
    const u16* bWr = wbf + 2 * 32768 + blk * 16384;
    const u16* bWo = wbf + 3 * 32768 + blk * 16384;
    const u16* bGp = wbf + 4 * 32768 + blk * 16384;
    const u16* bBp = wbf + 5 * 32768 + blk * 16384;
    const float* tdi = td + blk * 128;

    if (blk == 0)
      prep_kernel<1><<<2048, 256, 0, stream>>>(x, gamma, beta, ln_g, ln_b, outp, xn);
    else
      prep_kernel<0><<<2048, 256, 0, stream>>>(outp, nullptr, nullptr, ln_g + 128,
                                               ln_b + 128, nullptr, xn);

    gemm_S_kernel<<<1024, 256, 0, stream>>>(xn, bWk, tdi, Sbuf);
    scan2_kernel<<<256, 256, 0, stream>>>(Sbuf, tdi, ibuf);
    gemm_y_kernel<<<2048, 256, 0, stream>>>(xn, bWv, bWr, bWk, tdi, ibuf, ybuf);
    tail_kernel<<<1024, 512, 0, stream>>>(ybuf, bWo, bGp, bBp,
                                          gp_b + blk * 128, bp_b + blk * 128, outp);
  }
}